// Round 7
// baseline (88.714 us; speedup 1.0000x reference)
//
#include <hip/hip_runtime.h>
#include <hip/hip_bf16.h>

#define N2V    34816
#define BATCH  2048
#define E1V    32768
#define KFAN   16
#define INDIM  128
#define HID    256
#define OUTD   128
#define NNODES 200000

// ws layout (float32 units):
//   bs1   [256]        f32  @ 0
//   bs2   [128]        f32  @ 256
//   Wc1b  [256][256]   bf16 @ 384      (32768 f32 slots)
//   Wc2b  [128][512]   bf16 @ 33152    (32768 f32 slots)
//   xb    [200000][128] bf16 @ 65920   (12800000 f32 slots)
//   zg    [N2][256]    bf16 @ 12865920 (4456448 f32 slots)
//   agg1b [2048][256]  bf16 @ 17322368 (262144 f32 slots)
//   h1s   [2048][256]  bf16 @ 17584512 (262144 f32 slots)
#define OFF_BS1   0
#define OFF_BS2   256
#define OFF_WC1B  384
#define OFF_WC2B  33152
#define OFF_XB    65920
#define OFF_ZG    12865920
#define OFF_AGG1B 17322368
#define OFF_H1S   17584512

#define CONV_BLOCKS 12500         // 200000*128 / (256*8)
#define GATHER_BLOCKS (N2V / 16)  // 2176

typedef __attribute__((ext_vector_type(8))) short bf16x8;
typedef __attribute__((ext_vector_type(4))) float f32x4;

__device__ __forceinline__ float bf2f(short u) {
  union { unsigned u32; float f; } cv;
  cv.u32 = ((unsigned)(unsigned short)u) << 16;
  return cv.f;
}

__device__ __forceinline__ short f2b(float f) {
  __hip_bfloat16 h = __float2bfloat16(f);
  return *reinterpret_cast<short*>(&h);
}

// K0: stream-convert x (f32) -> xb (bf16). Pure streaming, ~153.6 MB.
__global__ __launch_bounds__(256) void convert_kernel(
    const float* __restrict__ x, __hip_bfloat16* __restrict__ xb) {
  const size_t base = ((size_t)blockIdx.x * 256 + threadIdx.x) * 8;
  float4 a = *reinterpret_cast<const float4*>(x + base);
  float4 b = *reinterpret_cast<const float4*>(x + base + 4);
  bf16x8 o = {f2b(a.x), f2b(a.y), f2b(a.z), f2b(a.w),
              f2b(b.x), f2b(b.y), f2b(b.z), f2b(b.w)};
  *reinterpret_cast<bf16x8*>((short*)xb + base) = o;
}

// K1: gather over bf16 table (blocks 0..2175) + weight prepack (last 256).
// gather: 16 nodes/block, 16 threads/node; thread owns one 16B slot (8 dims)
// of the 256B row; 17 outstanding row loads. zg[i] = [agg(128) | dec*self(128)].
__global__ __launch_bounds__(256) void gather_prepack_kernel(
    const __hip_bfloat16* __restrict__ xb, const float* __restrict__ t2,
    const float* __restrict__ n_times2, const int* __restrict__ nodes2,
    const int* __restrict__ nbr2, const float* __restrict__ tk,
    const float* __restrict__ W1n, const float* __restrict__ b1n,
    const float* __restrict__ W1h, const float* __restrict__ b1h,
    const float* __restrict__ W2n, const float* __restrict__ b2n,
    const float* __restrict__ W2h, const float* __restrict__ b2h,
    __hip_bfloat16* __restrict__ zg,
    __hip_bfloat16* __restrict__ Wc1b, __hip_bfloat16* __restrict__ Wc2b,
    float* __restrict__ bs1, float* __restrict__ bs2) {
  const int t = threadIdx.x;
  if (blockIdx.x >= GATHER_BLOCKS) {
    int idx = (blockIdx.x - GATHER_BLOCKS) * 256 + t;  // 0..65535
    // Wc1b[j][c]: j = layer-1 output col (256), c = k (256)
    int j1 = idx >> 8, c1 = idx & 255;
    float v1 = (c1 < 128) ? W1n[j1 * 128 + c1] : W1h[j1 * 128 + (c1 - 128)];
    Wc1b[idx] = __float2bfloat16(v1);
    // Wc2b[j][c]: j = output col (128), c = k (512)
    int j2 = idx >> 9, c2 = idx & 511;
    float v2 = (c2 < 256) ? W2n[j2 * 256 + c2] : W2h[j2 * 256 + (c2 - 256)];
    Wc2b[idx] = __float2bfloat16(v2);
    if (idx < 256) bs1[idx] = b1n[idx] + b1h[idx];
    if (idx < 128) bs2[idx] = b2n[idx] + b2h[idx];
    return;
  }

  const int i = blockIdx.x * 16 + (t >> 4);
  const int c = t & 15;  // 8-dim (16B) slot
  const short* __restrict__ xs = (const short*)xb;

  const int4* nb4 = reinterpret_cast<const int4*>(nbr2) + i * 4;
  int4 n0 = nb4[0], n1 = nb4[1], n2 = nb4[2], n3 = nb4[3];
  const int idx[16] = {n0.x, n0.y, n0.z, n0.w, n1.x, n1.y, n1.z, n1.w,
                       n2.x, n2.y, n2.z, n2.w, n3.x, n3.y, n3.z, n3.w};

  bf16x8 v[16];
#pragma unroll
  for (int k = 0; k < KFAN; ++k)
    v[k] = *reinterpret_cast<const bf16x8*>(xs + (size_t)idx[k] * INDIM + c * 8);
  bf16x8 sv = *reinterpret_cast<const bf16x8*>(xs + (size_t)nodes2[i] * INDIM + c * 8);
  const float dec = __expf(-tk[0] * (t2[i] - n_times2[i]));

  float acc[8] = {0.f, 0.f, 0.f, 0.f, 0.f, 0.f, 0.f, 0.f};
#pragma unroll
  for (int k = 0; k < KFAN; ++k)
#pragma unroll
    for (int e = 0; e < 8; ++e) acc[e] += bf2f(v[k][e]);

  bf16x8 pa = {f2b(acc[0]), f2b(acc[1]), f2b(acc[2]), f2b(acc[3]),
               f2b(acc[4]), f2b(acc[5]), f2b(acc[6]), f2b(acc[7])};
  bf16x8 pb;
#pragma unroll
  for (int e = 0; e < 8; ++e) pb[e] = f2b(bf2f(sv[e]) * dec);

  short* rowp = (short*)zg + (size_t)i * 256;
  *reinterpret_cast<bf16x8*>(rowp + c * 8) = pa;
  *reinterpret_cast<bf16x8*>(rowp + INDIM + c * 8) = pb;
}

// K2: gemm1, 32 rows/block, 4 waves (wave owns 64 cols; 2 mt x 4 nt x 8 ks).
// A staged in LDS, B from global (L2-hot). Epilogue: E1 blocks reduce each
// 16-row m-tile (= 1 segment) -> agg1b bf16; self blocks write h1s bf16.
__global__ __launch_bounds__(256) void gemm1_kernel(
    const __hip_bfloat16* __restrict__ zg,
    const __hip_bfloat16* __restrict__ Wc1b,
    const float* __restrict__ bs1,
    __hip_bfloat16* __restrict__ agg1b, __hip_bfloat16* __restrict__ h1s) {
  __shared__ __hip_bfloat16 z[32][264];  // row stride 528B
  const int t = threadIdx.x;
  const int i0 = blockIdx.x * 32;

  const char* src = (const char*)zg + (size_t)i0 * 512;
#pragma unroll
  for (int it = 0; it < 4; ++it) {
    int o = it * 4096 + t * 16;
    int row = o >> 9, colb = o & 511;
    bf16x8 v = *reinterpret_cast<const bf16x8*>(src + o);
    *reinterpret_cast<bf16x8*>((char*)&z[0][0] + row * 528 + colb) = v;
  }
  __syncthreads();

  const int wid = t >> 6;
  const int lane = t & 63;
  const int lr = lane & 15;
  const int lk8 = (lane >> 4) * 8;
  const int ncol0 = wid * 64;
  const short* __restrict__ wsrc = (const short*)Wc1b;

  f32x4 acc[2][4];
#pragma unroll
  for (int m = 0; m < 2; ++m)
#pragma unroll
    for (int n = 0; n < 4; ++n) acc[m][n] = (f32x4){0.f, 0.f, 0.f, 0.f};

#pragma unroll
  for (int ks = 0; ks < 8; ++ks) {
    const int kb = ks * 32 + lk8;
    bf16x8 a0 = *reinterpret_cast<const bf16x8*>((char*)&z[0][0] + lr * 528 + kb * 2);
    bf16x8 a1 = *reinterpret_cast<const bf16x8*>((char*)&z[0][0] + (16 + lr) * 528 + kb * 2);
#pragma unroll
    for (int nt = 0; nt < 4; ++nt) {
      bf16x8 b = *reinterpret_cast<const bf16x8*>(
          wsrc + (size_t)(ncol0 + nt * 16 + lr) * 256 + kb);
      acc[0][nt] = __builtin_amdgcn_mfma_f32_16x16x32_bf16(a0, b, acc[0][nt], 0, 0, 0);
      acc[1][nt] = __builtin_amdgcn_mfma_f32_16x16x32_bf16(a1, b, acc[1][nt], 0, 0, 0);
    }
  }

  if (i0 < E1V) {
    // C/D: col = lane&15, row = (lane>>4)*4 + q; m-tile mt == segment 2*blk+mt
#pragma unroll
    for (int nt = 0; nt < 4; ++nt) {
      const int col = ncol0 + nt * 16 + lr;
      const float bias = bs1[col];
#pragma unroll
      for (int mt = 0; mt < 2; ++mt) {
        float v = 0.f;
#pragma unroll
        for (int q = 0; q < 4; ++q) v += fmaxf(acc[mt][nt][q] + bias, 0.f);
        v += __shfl_xor(v, 16);
        v += __shfl_xor(v, 32);
        if (lane < 16) {
          const int seg = (i0 >> 4) + mt;
          agg1b[(size_t)seg * HID + col] = __float2bfloat16(v);
        }
      }
    }
  } else {
    const int orow = (lane >> 4) * 4;
#pragma unroll
    for (int nt = 0; nt < 4; ++nt) {
      const int col = ncol0 + nt * 16 + lr;
      const float bias = bs1[col];
#pragma unroll
      for (int mt = 0; mt < 2; ++mt) {
#pragma unroll
        for (int q = 0; q < 4; ++q) {
          const int row = i0 + mt * 16 + orow + q;
          h1s[(size_t)(row - E1V) * HID + col] =
              __float2bfloat16(fmaxf(acc[mt][nt][q] + bias, 0.f));
        }
      }
    }
  }
}

// K3: layer2 via MFMA. 128 blocks x 1 wave; block = 16 batch rows x 128 cols,
// K = 512 ([agg1b | dec*h1s]), 8 nt x 16 ks. out f32.
__global__ __launch_bounds__(64) void layer2_kernel(
    const __hip_bfloat16* __restrict__ agg1b, const __hip_bfloat16* __restrict__ h1s,
    const float* __restrict__ ts, const float* __restrict__ n_times1,
    const float* __restrict__ tk, const __hip_bfloat16* __restrict__ Wc2b,
    const float* __restrict__ bs2, float* __restrict__ out) {
  const int lane = threadIdx.x;
  const int b0 = blockIdx.x * 16;
  const int lr = lane & 15;
  const int lk8 = (lane >> 4) * 8;
  const int row = b0 + lr;  // A-fragment row for this lane

  const float dec = __expf(-tk[0] * (ts[row] - n_times1[row]));
  const short* __restrict__ ag = (const short*)agg1b;
  const short* __restrict__ hs = (const short*)h1s;
  const short* __restrict__ w2 = (const short*)Wc2b;

  f32x4 acc[8];
#pragma unroll
  for (int n = 0; n < 8; ++n) acc[n] = (f32x4){0.f, 0.f, 0.f, 0.f};

#pragma unroll
  for (int ks = 0; ks < 16; ++ks) {
    const int kb = ks * 32 + lk8;
    bf16x8 a;
    if (kb < HID) {
      a = *reinterpret_cast<const bf16x8*>(ag + (size_t)row * HID + kb);
    } else {
      bf16x8 hv = *reinterpret_cast<const bf16x8*>(hs + (size_t)row * HID + (kb - HID));
#pragma unroll
      for (int e = 0; e < 8; ++e) a[e] = f2b(bf2f(hv[e]) * dec);
    }
#pragma unroll
    for (int nt = 0; nt < 8; ++nt) {
      bf16x8 b = *reinterpret_cast<const bf16x8*>(
          w2 + (size_t)(nt * 16 + lr) * 512 + kb);
      acc[nt] = __builtin_amdgcn_mfma_f32_16x16x32_bf16(a, b, acc[nt], 0, 0, 0);
    }
  }

  const int orow = (lane >> 4) * 4;
#pragma unroll
  for (int nt = 0; nt < 8; ++nt) {
    const int col = nt * 16 + lr;
    const float bias = bs2[col];
#pragma unroll
    for (int q = 0; q < 4; ++q) {
      out[(size_t)(b0 + orow + q) * OUTD + col] = fmaxf(acc[nt][q] + bias, 0.f);
    }
  }
}

extern "C" void kernel_launch(void* const* d_in, const int* in_sizes, int n_in,
                              void* d_out, int out_size, void* d_ws, size_t ws_size,
                              hipStream_t stream) {
  const float* x        = (const float*)d_in[0];
  const float* ts       = (const float*)d_in[1];
  const float* t2       = (const float*)d_in[2];
  const float* n_times1 = (const float*)d_in[3];
  const float* n_times2 = (const float*)d_in[4];
  const float* W1n      = (const float*)d_in[5];
  const float* b1n      = (const float*)d_in[6];
  const float* W1h      = (const float*)d_in[7];
  const float* b1h      = (const float*)d_in[8];
  const float* W2n      = (const float*)d_in[9];
  const float* b2n      = (const float*)d_in[10];
  const float* W2h      = (const float*)d_in[11];
  const float* b2h      = (const float*)d_in[12];
  const float* tk       = (const float*)d_in[13];
  const int*   nodes2   = (const int*)d_in[14];
  const int*   nbr2     = (const int*)d_in[15];
  // d_in[16] = seg2, d_in[17] = seg1 — implicit (row-major repeat layout)

  float* ws = (float*)d_ws;
  float* bs1 = ws + OFF_BS1;
  float* bs2 = ws + OFF_BS2;
  __hip_bfloat16* Wc1b  = (__hip_bfloat16*)(ws + OFF_WC1B);
  __hip_bfloat16* Wc2b  = (__hip_bfloat16*)(ws + OFF_WC2B);
  __hip_bfloat16* xb    = (__hip_bfloat16*)(ws + OFF_XB);
  __hip_bfloat16* zg    = (__hip_bfloat16*)(ws + OFF_ZG);
  __hip_bfloat16* agg1b = (__hip_bfloat16*)(ws + OFF_AGG1B);
  __hip_bfloat16* h1s   = (__hip_bfloat16*)(ws + OFF_H1S);
  float* out = (float*)d_out;

  convert_kernel<<<CONV_BLOCKS, 256, 0, stream>>>(x, xb);
  gather_prepack_kernel<<<GATHER_BLOCKS + 256, 256, 0, stream>>>(
      xb, t2, n_times2, nodes2, nbr2, tk,
      W1n, b1n, W1h, b1h, W2n, b2n, W2h, b2h,
      zg, Wc1b, Wc2b, bs1, bs2);
  gemm1_kernel<<<N2V / 32, 256, 0, stream>>>(zg, Wc1b, bs1, agg1b, h1s);
  layer2_kernel<<<BATCH / 16, 64, 0, stream>>>(agg1b, h1s, ts, n_times1, tk,
                                               Wc2b, bs2, out);
}

// Round 9
// 77.002 us; speedup vs baseline: 1.1521x; 1.1521x over previous
//
#include <hip/hip_runtime.h>
#include <hip/hip_bf16.h>

#define N2V    34816
#define BATCH  2048
#define E1V    32768
#define KFAN   16
#define INDIM  128
#define HID    256
#define OUTD   128

// ws layout (float32 units):
//   bs1   [256]        f32  @ 0
//   bs2   [128]        f32  @ 256
//   Wc1b  [256][256]   bf16 @ 384      (32768 f32 slots)
//   Wc2b  [128][512]   bf16 @ 33152    (32768 f32 slots)
//   agg1b [2048][256]  bf16 @ 65920    (262144 f32 slots)
//   h1s   [2048][256]  bf16 @ 328064   (262144 f32 slots)
#define OFF_BS1   0
#define OFF_BS2   256
#define OFF_WC1B  384
#define OFF_WC2B  33152
#define OFF_AGG1B 65920
#define OFF_H1S   328064

typedef __attribute__((ext_vector_type(8))) short bf16x8;
typedef __attribute__((ext_vector_type(4))) short short4v;
typedef __attribute__((ext_vector_type(4))) float f32x4;

__device__ __forceinline__ float bf2f(short u) {
  union { unsigned u32; float f; } cv;
  cv.u32 = ((unsigned)(unsigned short)u) << 16;
  return cv.f;
}

__device__ __forceinline__ short f2b(float f) {
  __hip_bfloat16 h = __float2bfloat16(f);
  return *reinterpret_cast<short*>(&h);
}

// K0: weight prepack (256 blocks x 256 thr).
__global__ __launch_bounds__(256) void prepack_kernel(
    const float* __restrict__ W1n, const float* __restrict__ b1n,
    const float* __restrict__ W1h, const float* __restrict__ b1h,
    const float* __restrict__ W2n, const float* __restrict__ b2n,
    const float* __restrict__ W2h, const float* __restrict__ b2h,
    __hip_bfloat16* __restrict__ Wc1b, __hip_bfloat16* __restrict__ Wc2b,
    float* __restrict__ bs1, float* __restrict__ bs2) {
  int idx = blockIdx.x * 256 + threadIdx.x;  // 0..65535
  // Wc1b[j][c]: j = layer-1 output col (256), c = k (256)
  int j1 = idx >> 8, c1 = idx & 255;
  float v1 = (c1 < 128) ? W1n[j1 * 128 + c1] : W1h[j1 * 128 + (c1 - 128)];
  Wc1b[idx] = __float2bfloat16(v1);
  // Wc2b[j][c]: j = output col (128), c = k (512)
  int j2 = idx >> 9, c2 = idx & 511;
  float v2 = (c2 < 256) ? W2n[j2 * 256 + c2] : W2h[j2 * 256 + (c2 - 256)];
  Wc2b[idx] = __float2bfloat16(v2);
  if (idx < 256) bs1[idx] = b1n[idx] + b1h[idx];
  if (idx < 128) bs2[idx] = b2n[idx] + b2h[idx];
}

// K1: fused gather + gemm1. 16 nodes/block (2176 blocks, 4 waves).
// Gather phase: 16 thr/node, thread owns float4 slots {c, c+16} of the f32
// row; sums 16 neighbors + decayed self -> LDS bf16 z[16][264].
// GEMM phase: wave owns 64 cols; 1 m-tile x 4 nt x 8 ks of 16x16x32 MFMA,
// B straight from global (L2-hot 128KB). Epilogue: E1 blocks (tile == one
// segment of 16) reduce rows -> agg1b bf16; self blocks write h1s bf16.
__global__ __launch_bounds__(256) void fused1_kernel(
    const float* __restrict__ x, const float* __restrict__ t2,
    const float* __restrict__ n_times2, const int* __restrict__ nodes2,
    const int* __restrict__ nbr2, const float* __restrict__ tk,
    const __hip_bfloat16* __restrict__ Wc1b, const float* __restrict__ bs1,
    __hip_bfloat16* __restrict__ agg1b, __hip_bfloat16* __restrict__ h1s) {
  __shared__ __hip_bfloat16 z[16][264];  // row stride 528B
  const int t = threadIdx.x;
  const int i0 = blockIdx.x * 16;
  {
    const int r = t >> 4;
    const int c = t & 15;
    const int i = i0 + r;
    const float4* __restrict__ x4 = (const float4*)x;

    const int4* nb4 = reinterpret_cast<const int4*>(nbr2) + i * 4;
    int4 n0 = nb4[0], n1 = nb4[1], n2 = nb4[2], n3 = nb4[3];
    const int idx[16] = {n0.x, n0.y, n0.z, n0.w, n1.x, n1.y, n1.z, n1.w,
                         n2.x, n2.y, n2.z, n2.w, n3.x, n3.y, n3.z, n3.w};

    float4 s0 = {0.f, 0.f, 0.f, 0.f};
    float4 s1 = {0.f, 0.f, 0.f, 0.f};
#pragma unroll
    for (int k = 0; k < KFAN; ++k) {
      const float4* rp = x4 + (size_t)idx[k] * 32;
      float4 v0 = rp[c];
      float4 v1 = rp[16 + c];
      s0.x += v0.x; s0.y += v0.y; s0.z += v0.z; s0.w += v0.w;
      s1.x += v1.x; s1.y += v1.y; s1.z += v1.z; s1.w += v1.w;
    }
    const float dec = __expf(-tk[0] * (t2[i] - n_times2[i]));
    const float4* sp = x4 + (size_t)nodes2[i] * 32;
    float4 u0 = sp[c];
    float4 u1 = sp[16 + c];

    char* zrow = (char*)&z[0][0] + r * 528;
    short4v p;
    p = (short4v){f2b(s0.x), f2b(s0.y), f2b(s0.z), f2b(s0.w)};
    *reinterpret_cast<short4v*>(zrow + c * 8) = p;
    p = (short4v){f2b(s1.x), f2b(s1.y), f2b(s1.z), f2b(s1.w)};
    *reinterpret_cast<short4v*>(zrow + 128 + c * 8) = p;
    p = (short4v){f2b(u0.x * dec), f2b(u0.y * dec), f2b(u0.z * dec), f2b(u0.w * dec)};
    *reinterpret_cast<short4v*>(zrow + 256 + c * 8) = p;
    p = (short4v){f2b(u1.x * dec), f2b(u1.y * dec), f2b(u1.z * dec), f2b(u1.w * dec)};
    *reinterpret_cast<short4v*>(zrow + 384 + c * 8) = p;
  }
  __syncthreads();

  const int wid = t >> 6;
  const int lane = t & 63;
  const int lr = lane & 15;
  const int lk8 = (lane >> 4) * 8;
  const int ncol0 = wid * 64;
  const short* __restrict__ wsrc = (const short*)Wc1b;

  f32x4 acc[4];
#pragma unroll
  for (int n = 0; n < 4; ++n) acc[n] = (f32x4){0.f, 0.f, 0.f, 0.f};

#pragma unroll
  for (int ks = 0; ks < 8; ++ks) {
    const int kb = ks * 32 + lk8;
    bf16x8 a = *reinterpret_cast<const bf16x8*>((char*)&z[0][0] + lr * 528 + kb * 2);
#pragma unroll
    for (int nt = 0; nt < 4; ++nt) {
      bf16x8 b = *reinterpret_cast<const bf16x8*>(
          wsrc + (size_t)(ncol0 + nt * 16 + lr) * 256 + kb);
      acc[nt] = __builtin_amdgcn_mfma_f32_16x16x32_bf16(a, b, acc[nt], 0, 0, 0);
    }
  }

  if (i0 < E1V) {
    // tile == segment blockIdx.x; reduce 16 rows of relu(acc+bias)
#pragma unroll
    for (int nt = 0; nt < 4; ++nt) {
      const int col = ncol0 + nt * 16 + lr;
      const float bias = bs1[col];
      float v = 0.f;
#pragma unroll
      for (int q = 0; q < 4; ++q) v += fmaxf(acc[nt][q] + bias, 0.f);
      v += __shfl_xor(v, 16);
      v += __shfl_xor(v, 32);
      if (lane < 16) {
        agg1b[(size_t)blockIdx.x * HID + col] = __float2bfloat16(v);
      }
    }
  } else {
    const int orow = (lane >> 4) * 4;
#pragma unroll
    for (int nt = 0; nt < 4; ++nt) {
      const int col = ncol0 + nt * 16 + lr;
      const float bias = bs1[col];
#pragma unroll
      for (int q = 0; q < 4; ++q) {
        const int row = i0 - E1V + orow + q;
        h1s[(size_t)row * HID + col] =
            __float2bfloat16(fmaxf(acc[nt][q] + bias, 0.f));
      }
    }
  }
}

// K2: layer2 via MFMA. 128 blocks x 1 wave; block = 16 batch rows x 128 cols,
// K = 512 ([agg1b | dec*h1s]), 8 nt x 16 ks. out f32.
__global__ __launch_bounds__(64) void layer2_kernel(
    const __hip_bfloat16* __restrict__ agg1b, const __hip_bfloat16* __restrict__ h1s,
    const float* __restrict__ ts, const float* __restrict__ n_times1,
    const float* __restrict__ tk, const __hip_bfloat16* __restrict__ Wc2b,
    const float* __restrict__ bs2, float* __restrict__ out) {
  const int lane = threadIdx.x;
  const int b0 = blockIdx.x * 16;
  const int lr = lane & 15;
  const int lk8 = (lane >> 4) * 8;
  const int row = b0 + lr;  // A-fragment row for this lane

  const float dec = __expf(-tk[0] * (ts[row] - n_times1[row]));
  const short* __restrict__ ag = (const short*)agg1b;
  const short* __restrict__ hs = (const short*)h1s;
  const short* __restrict__ w2 = (const short*)Wc2b;

  f32x4 acc[8];
#pragma unroll
  for (int n = 0; n < 8; ++n) acc[n] = (f32x4){0.f, 0.f, 0.f, 0.f};

#pragma unroll
  for (int ks = 0; ks < 16; ++ks) {
    const int kb = ks * 32 + lk8;
    bf16x8 a;
    if (kb < HID) {
      a = *reinterpret_cast<const bf16x8*>(ag + (size_t)row * HID + kb);
    } else {
      bf16x8 hv = *reinterpret_cast<const bf16x8*>(hs + (size_t)row * HID + (kb - HID));
#pragma unroll
      for (int e = 0; e < 8; ++e) a[e] = f2b(bf2f(hv[e]) * dec);
    }
#pragma unroll
    for (int nt = 0; nt < 8; ++nt) {
      bf16x8 b = *reinterpret_cast<const bf16x8*>(
          w2 + (size_t)(nt * 16 + lr) * 512 + kb);
      acc[nt] = __builtin_amdgcn_mfma_f32_16x16x32_bf16(a, b, acc[nt], 0, 0, 0);
    }
  }

  const int orow = (lane >> 4) * 4;
#pragma unroll
  for (int nt = 0; nt < 8; ++nt) {
    const int col = nt * 16 + lr;
    const float bias = bs2[col];
#pragma unroll
    for (int q = 0; q < 4; ++q) {
      out[(size_t)(b0 + orow + q) * OUTD + col] = fmaxf(acc[nt][q] + bias, 0.f);
    }
  }
}

extern "C" void kernel_launch(void* const* d_in, const int* in_sizes, int n_in,
                              void* d_out, int out_size, void* d_ws, size_t ws_size,
                              hipStream_t stream) {
  const float* x        = (const float*)d_in[0];
  const float* ts       = (const float*)d_in[1];
  const float* t2       = (const float*)d_in[2];
  const float* n_times1 = (const float*)d_in[3];
  const float* n_times2 = (const float*)d_in[4];
  const float* W1n      = (const float*)d_in[5];
  const float* b1n      = (const float*)d_in[6];
  const float* W1h      = (const float*)d_in[7];
  const float* b1h      = (const float*)d_in[8];
  const float* W2n      = (const float*)d_in[9];
  const float* b2n      = (const float*)d_in[10];
  const float* W2h      = (const float*)d_in[11];
  const float* b2h      = (const float*)d_in[12];
  const float* tk       = (const float*)d_in[13];
  const int*   nodes2   = (const int*)d_in[14];
  const int*   nbr2     = (const int*)d_in[15];
  // d_in[16] = seg2, d_in[17] = seg1 — implicit (row-major repeat layout)

  float* ws = (float*)d_ws;
  float* bs1 = ws + OFF_BS1;
  float* bs2 = ws + OFF_BS2;
  __hip_bfloat16* Wc1b  = (__hip_bfloat16*)(ws + OFF_WC1B);
  __hip_bfloat16* Wc2b  = (__hip_bfloat16*)(ws + OFF_WC2B);
  __hip_bfloat16* agg1b = (__hip_bfloat16*)(ws + OFF_AGG1B);
  __hip_bfloat16* h1s   = (__hip_bfloat16*)(ws + OFF_H1S);
  float* out = (float*)d_out;

  prepack_kernel<<<256, 256, 0, stream>>>(W1n, b1n, W1h, b1h,
                                          W2n, b2n, W2h, b2h,
                                          Wc1b, Wc2b, bs1, bs2);
  fused1_kernel<<<N2V / 16, 256, 0, stream>>>(x, t2, n_times2, nodes2, nbr2, tk,
                                              Wc1b, bs1, agg1b, h1s);
  layer2_kernel<<<BATCH / 16, 64, 0, stream>>>(agg1b, h1s, ts, n_times1, tk,
                                               Wc2b, bs2, out);
}